// Round 9
// baseline (817.833 us; speedup 1.0000x reference)
//
#include <hip/hip_runtime.h>
#include <math.h>

#define N_ROWS 4096
#define E_DIM  512
#define C_CLS  50257
#define NIT    99           // ceil(50257/512) 512-col iterations
#define NCT    792          // partials per row: NIT * 8 waves (64 cols each)
#define NGRP   16           // cgroups
#define COS_M  (-0.6536436208636119f)   // cos(4.0)
#define SIN_M  (-0.7568024953079282f)   // sin(4.0)
#define EPSN   1e-12f

#define WAITCNT_VM0 0x0F70   // vmcnt(0), lgkm/exp ignored

typedef __bf16 bf16x8 __attribute__((ext_vector_type(8)));
typedef float  f32x4  __attribute__((ext_vector_type(4)));
typedef unsigned short ushort8 __attribute__((ext_vector_type(8)));

__device__ inline unsigned short f2bf(float f) {
  unsigned int u = __float_as_uint(f);
  u += 0x7FFFu + ((u >> 16) & 1u);     // round-to-nearest-even
  return (unsigned short)(u >> 16);
}

// w row L2-normalize, wave-private (no barriers): 4 rows/block, 1 wave/row.
__global__ __launch_bounds__(256) void k_norm_w(const float* __restrict__ src,
                                                unsigned short* __restrict__ dst) {
  int row = blockIdx.x * 4 + (threadIdx.x >> 6);
  if (row >= C_CLS) return;
  int lane = threadIdx.x & 63;
  const float4* p = (const float4*)(src + (size_t)row * E_DIM);
  float4 v0 = p[lane * 2], v1 = p[lane * 2 + 1];
  float ss = v0.x*v0.x + v0.y*v0.y + v0.z*v0.z + v0.w*v0.w
           + v1.x*v1.x + v1.y*v1.y + v1.z*v1.z + v1.w*v1.w;
  #pragma unroll
  for (int m = 32; m > 0; m >>= 1) ss += __shfl_xor(ss, m, 64);
  float inv = 1.0f / fmaxf(sqrtf(ss), EPSN);
  ushort8 o;
  o[0]=f2bf(v0.x*inv); o[1]=f2bf(v0.y*inv); o[2]=f2bf(v0.z*inv); o[3]=f2bf(v0.w*inv);
  o[4]=f2bf(v1.x*inv); o[5]=f2bf(v1.y*inv); o[6]=f2bf(v1.z*inv); o[7]=f2bf(v1.w*inv);
  *(ushort8*)(dst + (size_t)row * E_DIM + lane * 8) = o;
}

// x row L2-normalize + precise fp32 target cosine (fused). 1 block/row, 256 thr.
__global__ __launch_bounds__(256) void k_norm_x(const float* __restrict__ x,
                                                const float* __restrict__ w,
                                                const int* __restrict__ label,
                                                unsigned short* __restrict__ nx,
                                                float* __restrict__ tv) {
  int row = blockIdx.x;
  int lab = label[row];
  int tid = threadIdx.x;
  const float2* px = (const float2*)(x + (size_t)row * E_DIM);
  const float2* pw = (const float2*)(w + (size_t)lab * E_DIM);
  float2 a = px[tid], b = pw[tid];
  float sx = a.x*a.x + a.y*a.y;
  float sw = b.x*b.x + b.y*b.y;
  float sd = a.x*b.x + a.y*b.y;
  #pragma unroll
  for (int off = 32; off > 0; off >>= 1) {
    sx += __shfl_down(sx, off, 64);
    sw += __shfl_down(sw, off, 64);
    sd += __shfl_down(sd, off, 64);
  }
  __shared__ float sb[3][4];
  if ((tid & 63) == 0) {
    sb[0][tid >> 6] = sx; sb[1][tid >> 6] = sw; sb[2][tid >> 6] = sd;
  }
  __syncthreads();
  float SX = sb[0][0] + sb[0][1] + sb[0][2] + sb[0][3];
  float inv = 1.0f / fmaxf(sqrtf(SX), EPSN);
  ushort2 o;
  o.x = f2bf(a.x * inv);
  o.y = f2bf(a.y * inv);
  ((ushort2*)(nx + (size_t)row * E_DIM))[tid] = o;
  if (tid == 0) {
    float SW = sb[1][0] + sb[1][1] + sb[1][2] + sb[1][3];
    float SD = sb[2][0] + sb[2][1] + sb[2][2] + sb[2][3];
    tv[row] = SD / (fmaxf(sqrtf(SX), EPSN) * fmaxf(sqrtf(SW), EPSN));
  }
}

// A-resident GEMM (cos = nx.nw^T) + fused exp-sum.
// Block = 512 thr (8 waves), A-tile 128 rows x 512 K in LDS (128 KB), loaded
// ONCE (global_load_lds, fragment order) -> one barrier, then ZERO barriers.
// Each wave owns a 128x64 output slab per 512-col iteration: B fragments
// stream global->register (3-deep rotation, no LDS), A fragments ds_read from
// the static tile. No inter-wave hazards => no lgkm drains, no convoys.
// Grid (NGRP,32), cgroup fastest: XCD ~ linear%8 = cgroup%8, so each XCD's L2
// streams one contiguous B range shared by its 32 resident rtile-blocks.
// No max-prescan: cos in [-1,1] so exp() is safe; partials are plain sums.
__global__ __launch_bounds__(512, 2) void k_gemm(const unsigned short* __restrict__ nx,
                                                 const unsigned short* __restrict__ nw,
                                                 const int* __restrict__ label,
                                                 float* __restrict__ pl,
                                                 float* __restrict__ tbf) {
  __shared__ bf16x8 ldsA[128 * 64];   // 128 chunks x 1 KB = 128 KB

  int cgrp = blockIdx.x;               // 0..15 fastest -> XCD = cgrp%8
  int rtile = blockIdx.y;              // 0..31
  int tid = threadIdx.x;
  int wave = tid >> 6;                 // 0..7
  int lane = tid & 63;
  int q = lane >> 4;
  int l15 = lane & 15;
  int rowTile = rtile * 128;

  // ---- Prologue: stage A[rowTile..+128) x K into LDS in fragment order.
  // Chunk c = ks*8 + g16 (ks = K-stage 0..15, g16 = row-group 0..7): lane
  // (q,l15) supplies A[g16*16+l15][ks*32+q*8..+7] at chunk base + lane*16.
  #pragma unroll
  for (int t = 0; t < 16; t++) {
    int c = wave * 16 + t;
    int ks = c >> 3, g16 = c & 7;
    const unsigned short* src =
        nx + (size_t)(rowTile + g16 * 16 + l15) * E_DIM + ks * 32 + q * 8;
    __builtin_amdgcn_global_load_lds(
        (const __attribute__((address_space(1))) void*)src,
        (__attribute__((address_space(3))) void*)(&ldsA[c * 64]), 16, 0, 0);
  }
  __builtin_amdgcn_s_waitcnt(WAITCNT_VM0);
  __syncthreads();   // the ONLY barrier in this kernel

  // ---- Iterate this cgroup's 512-col slabs.
  int itBeg = (cgrp * NIT) / NGRP;
  int itEnd = ((cgrp + 1) * NIT) / NGRP;
  for (int it = itBeg; it < itEnd; it++) {
    int colBase = it * 512 + wave * 64;
    const unsigned short* gB[4];
    #pragma unroll
    for (int j = 0; j < 4; j++) {
      int cls = colBase + j * 16 + l15;
      if (cls >= C_CLS) cls = C_CLS - 1;      // clamp; masked in epilogue
      gB[j] = nw + (size_t)cls * E_DIM + q * 8;
    }

    // B rotation: slot s holds stage data for kt with kt%3 == s.
    bf16x8 bfr[3][4];
    #pragma unroll
    for (int j = 0; j < 4; j++) {
      bfr[0][j] = *(const bf16x8*)(gB[j]);
      bfr[1][j] = *(const bf16x8*)(gB[j] + 32);
    }

    f32x4 acc[8][4] = {};

    #pragma unroll
    for (int kt = 0; kt < 16; kt++) {
      int s = kt % 3;
      // Prefetch stage kt+2 B into slot (kt+2)%3.
      if (kt + 2 < 16) {
        int s2 = (kt + 2) % 3;
        #pragma unroll
        for (int j = 0; j < 4; j++)
          bfr[s2][j] = *(const bf16x8*)(gB[j] + (kt + 2) * 32);
      }
      // A fragments for stage kt from the static LDS tile.
      bf16x8 afr[8];
      #pragma unroll
      for (int i = 0; i < 8; i++)
        afr[i] = ldsA[(kt * 8 + i) * 64 + lane];
      #pragma unroll
      for (int j = 0; j < 4; j++)
        #pragma unroll
        for (int i = 0; i < 8; i++)
          acc[i][j] = __builtin_amdgcn_mfma_f32_16x16x32_bf16(afr[i], bfr[s][j],
                                                              acc[i][j], 0, 0, 0);
    }

    // Epilogue for this slab. C/D: row = 4*q + reg (within 16), col = l15.
    #pragma unroll
    for (int i = 0; i < 8; i++) {
      #pragma unroll
      for (int reg = 0; reg < 4; reg++) {
        int grow = rowTile + i * 16 + 4 * q + reg;
        int lab = label[grow];
        float e = 0.f;
        #pragma unroll
        for (int j = 0; j < 4; j++) {
          int col = colBase + j * 16 + l15;
          float v = acc[i][j][reg];
          if (col < C_CLS) {
            e += __expf(v);
            if (col == lab) tbf[grow] = v;   // bf16-GEMM cos at label position
          }
        }
        #pragma unroll
        for (int m = 1; m < 16; m <<= 1) e += __shfl_xor(e, m, 64);
        if (l15 == 0) pl[(size_t)grow * NCT + it * 8 + wave] = e;
      }
    }
  }
}

// Sum per-tile exp-sums -> row denominator, swap in margin logit, mean-reduce.
__global__ __launch_bounds__(256) void k_reduce(const float* __restrict__ pl,
                                               const float* __restrict__ tv,
                                               const float* __restrict__ tbf,
                                               float* __restrict__ out) {
  int row = blockIdx.x;
  int tid = threadIdx.x;
  float s = 0.f;
  for (int j = tid; j < NCT; j += 256) s += pl[(size_t)row * NCT + j];
  __shared__ float sb[256];
  sb[tid] = s;
  __syncthreads();
  for (int k = 128; k > 0; k >>= 1) {
    if (tid < k) sb[tid] += sb[tid + k];
    __syncthreads();
  }
  if (tid == 0) {
    float S = sb[0];
    float t = tv[row];
    float tb = tbf[row];
    float sint = sqrtf(fmaxf(0.f, 1.f - t * t));
    float cosm = t * COS_M - sint * SIN_M;
    float Sp = S - __expf(tb) + __expf(cosm);   // replace target logit
    float loss = logf(Sp) - cosm;
    atomicAdd(out, loss * (1.0f / N_ROWS));
  }
}

extern "C" void kernel_launch(void* const* d_in, const int* in_sizes, int n_in,
                              void* d_out, int out_size, void* d_ws, size_t ws_size,
                              hipStream_t stream) {
  const float* x = (const float*)d_in[0];
  const int* label = (const int*)d_in[1];
  const float* w = (const float*)d_in[2];
  float* out = (float*)d_out;
  char* ws = (char*)d_ws;

  size_t off = 0;
  unsigned short* nx = (unsigned short*)(ws + off); off += (size_t)N_ROWS * E_DIM * 2;  // 4 MB
  unsigned short* nw = (unsigned short*)(ws + off); off += (size_t)C_CLS * E_DIM * 2;   // 51.5 MB
  float* tv  = (float*)(ws + off); off += (size_t)N_ROWS * 4;
  float* tbf = (float*)(ws + off); off += (size_t)N_ROWS * 4;
  float* pl  = (float*)(ws + off); off += (size_t)N_ROWS * NCT * 4;                     // 13 MB

  hipMemsetAsync(d_out, 0, sizeof(float), stream);
  k_norm_w<<<(C_CLS + 3) / 4, 256, 0, stream>>>(w, nw);
  k_norm_x<<<N_ROWS, 256, 0, stream>>>(x, w, label, nx, tv);
  dim3 g(NGRP, N_ROWS / 128);
  k_gemm<<<g, 512, 0, stream>>>(nx, nw, label, pl, tbf);
  k_reduce<<<N_ROWS, 256, 0, stream>>>(pl, tv, tbf, out);
}